// Round 1
// baseline (23878.825 us; speedup 1.0000x reference)
//
#include <hip/hip_runtime.h>

#define D 128
#define M 64

__global__ __launch_bounds__(256, 2) void gmm_kernel(
    const float* __restrict__ x, const float* __restrict__ mem,
    const float* __restrict__ gw, const float* __restrict__ gb,
    float* __restrict__ out, int n)
{
    __shared__ float smem[M * D];   // 32 KB: full memory matrix, row-major
    __shared__ float sgw[D];

    // cooperative staging: 8192 floats = 2048 float4 over 256 threads
    for (int i = threadIdx.x; i < (M * D) / 4; i += 256) {
        ((float4*)smem)[i] = ((const float4*)mem)[i];
    }
    if (threadIdx.x < D / 4) {
        ((float4*)sgw)[threadIdx.x] = ((const float4*)gw)[threadIdx.x];
    }
    __syncthreads();

    int row = blockIdx.x * 256 + threadIdx.x;
    if (row >= n) return;   // no __syncthreads after this point

    const float4* __restrict__ xr = (const float4*)(x + (size_t)row * D);
    float4* __restrict__ outr = (float4*)(out + (size_t)row * D);

    float sim[M];
#pragma unroll
    for (int m = 0; m < M; ++m) sim[m] = 0.0f;
    float g0 = 0.f, g1 = 0.f, g2 = 0.f, g3 = 0.f;

    // ---- pass 1: sim[m] = x . mem[m], gate partial ----
#pragma unroll
    for (int c = 0; c < 4; ++c) {           // 4 chunks of 32 dims
        float4 xc[8];
#pragma unroll
        for (int j = 0; j < 8; ++j) xc[j] = xr[c * 8 + j];

        const float4* gw4 = (const float4*)(sgw + c * 32);
#pragma unroll
        for (int j = 0; j < 8; ++j) {
            float4 w = gw4[j];
            g0 += xc[j].x * w.x; g1 += xc[j].y * w.y;
            g2 += xc[j].z * w.z; g3 += xc[j].w * w.w;
        }
#pragma unroll
        for (int m = 0; m < M; ++m) {
            const float4* mr = (const float4*)(smem + m * D + c * 32);
            float s = sim[m];
#pragma unroll
            for (int j = 0; j < 8; ++j) {
                float4 v = mr[j];   // wave-uniform broadcast read
                s += xc[j].x * v.x; s += xc[j].y * v.y;
                s += xc[j].z * v.z; s += xc[j].w * v.w;
            }
            sim[m] = s;
        }
    }

    float gate = (g0 + g1) + (g2 + g3) + gb[0];
    float g = 1.0f / (1.0f + __expf(-gate));

    // ---- softmax over the 64 slots, per-lane (no cross-lane ops) ----
    float mx = sim[0];
#pragma unroll
    for (int m = 1; m < M; ++m) mx = fmaxf(mx, sim[m]);
    float sum = 0.0f;
#pragma unroll
    for (int m = 0; m < M; ++m) {
        float e = __expf(sim[m] - mx);
        sim[m] = e;                 // sim now holds unnormalized attn
        sum += e;
    }
    float grs = g / sum;            // fold softmax normalization into gate
    float gi  = 1.0f - g;

    // ---- pass 2: out = grs * (attn_unnorm @ mem) + gi * x ----
#pragma unroll
    for (int c = 0; c < 4; ++c) {
        float4 acc[8];
#pragma unroll
        for (int j = 0; j < 8; ++j) acc[j] = make_float4(0.f, 0.f, 0.f, 0.f);
#pragma unroll
        for (int m = 0; m < M; ++m) {
            float a = sim[m];
            const float4* mr = (const float4*)(smem + m * D + c * 32);
#pragma unroll
            for (int j = 0; j < 8; ++j) {
                float4 v = mr[j];   // broadcast read
                acc[j].x += a * v.x; acc[j].y += a * v.y;
                acc[j].z += a * v.z; acc[j].w += a * v.w;
            }
        }
#pragma unroll
        for (int j = 0; j < 8; ++j) {
            float4 xv = xr[c * 8 + j];      // re-read x (L2/L3-hot)
            float4 o;
            o.x = grs * acc[j].x + gi * xv.x;
            o.y = grs * acc[j].y + gi * xv.y;
            o.z = grs * acc[j].z + gi * xv.z;
            o.w = grs * acc[j].w + gi * xv.w;
            outr[c * 8 + j] = o;
        }
    }
}

extern "C" void kernel_launch(void* const* d_in, const int* in_sizes, int n_in,
                              void* d_out, int out_size, void* d_ws, size_t ws_size,
                              hipStream_t stream) {
    const float* x   = (const float*)d_in[0];
    const float* mem = (const float*)d_in[1];
    const float* gw  = (const float*)d_in[2];
    const float* gb  = (const float*)d_in[3];
    float* out = (float*)d_out;
    int n = in_sizes[0] / D;   // number of rows

    int grid = (n + 255) / 256;
    gmm_kernel<<<grid, 256, 0, stream>>>(x, mem, gw, gb, out, n);
}